// Round 1
// baseline (306.587 us; speedup 1.0000x reference)
//
#include <hip/hip_runtime.h>
#include <stdint.h>

static constexpr int nS   = 16384;
static constexpr int nD   = 1024;
static constexpr int nE   = 32;
static constexpr int nH   = 1024;
static constexpr int nCAP = 512;

static constexpr int GT = 64;   // tokens per gate block
static constexpr int GB = nS / GT; // 256 gate blocks

typedef __bf16 bf16x8 __attribute__((ext_vector_type(8)));
typedef float  f32x4  __attribute__((ext_vector_type(4)));

static __device__ __forceinline__ unsigned short f2bf(float f) {
    __bf16 h = (__bf16)f;
    return __builtin_bit_cast(unsigned short, h);
}

static __device__ __forceinline__ void gload16(const void* g, void* l) {
    __builtin_amdgcn_global_load_lds(
        (const __attribute__((address_space(1))) void*)g,
        (__attribute__((address_space(3))) void*)l, 16, 0, 0);
}

// ---------------- init: inv_slot = -1, me = 0 ----------------
__global__ void k_init(int* __restrict__ inv_slot, float* __restrict__ me) {
    int i = blockIdx.x * 256 + threadIdx.x;
    if (i < nE * nCAP) inv_slot[i] = -1;
    if (i < nE) me[i] = 0.f;
}

// ---------------- gating: logits fp32, softmax, argmax, x->bf16 ----------------
__global__ __launch_bounds__(128) void k_gate(
    const float* __restrict__ x, const float* __restrict__ wg,
    unsigned short* __restrict__ xbf, int* __restrict__ idxo,
    float* __restrict__ gateval, int* __restrict__ counts,
    float* __restrict__ me_g)
{
    __shared__ float xs[GT][65];
    __shared__ float wgs[nE][65];
    __shared__ float gl[GT][nE + 1];
    __shared__ int   hist[nE];

    const int tid = threadIdx.x;
    const int tb  = blockIdx.x * GT;
    if (tid < nE) hist[tid] = 0;

    const int t0 = (tid >> 3) * 4;   // 16 groups * 4 tokens
    const int e0 = (tid & 7) * 4;    // 8 groups * 4 experts
    float acc[4][4] = {};

    for (int ch = 0; ch < nD / 64; ++ch) {
        // stage wg chunk [32][64]
#pragma unroll
        for (int i = 0; i < 4; ++i) {
            int f = tid + i * 128;           // 0..511 float4
            int r = f >> 4, c4 = f & 15;
            const float4 v = *(const float4*)&wg[(size_t)r * nD + ch * 64 + c4 * 4];
            wgs[r][c4*4+0] = v.x; wgs[r][c4*4+1] = v.y;
            wgs[r][c4*4+2] = v.z; wgs[r][c4*4+3] = v.w;
        }
        // stage x chunk [64][64] + emit bf16
#pragma unroll
        for (int i = 0; i < 8; ++i) {
            int f = tid + i * 128;           // 0..1023 float4
            int r = f >> 4, c4 = f & 15;
            size_t go = (size_t)(tb + r) * nD + ch * 64 + c4 * 4;
            const float4 v = *(const float4*)&x[go];
            xs[r][c4*4+0] = v.x; xs[r][c4*4+1] = v.y;
            xs[r][c4*4+2] = v.z; xs[r][c4*4+3] = v.w;
            unsigned long long pk = (unsigned long long)f2bf(v.x)
                | ((unsigned long long)f2bf(v.y) << 16)
                | ((unsigned long long)f2bf(v.z) << 32)
                | ((unsigned long long)f2bf(v.w) << 48);
            *(unsigned long long*)&xbf[go] = pk;
        }
        __syncthreads();
#pragma unroll 4
        for (int k = 0; k < 64; ++k) {
            float xa[4], wb[4];
#pragma unroll
            for (int i = 0; i < 4; ++i) xa[i] = xs[t0 + i][k];
#pragma unroll
            for (int j = 0; j < 4; ++j) wb[j] = wgs[e0 + j][k];
#pragma unroll
            for (int i = 0; i < 4; ++i)
#pragma unroll
                for (int j = 0; j < 4; ++j) acc[i][j] += xa[i] * wb[j];
        }
        __syncthreads();
    }

#pragma unroll
    for (int i = 0; i < 4; ++i)
#pragma unroll
        for (int j = 0; j < 4; ++j) gl[t0 + i][e0 + j] = acc[i][j];
    __syncthreads();

    if (tid < GT) {
        float mx = gl[tid][0]; int bi = 0;
#pragma unroll
        for (int e = 1; e < nE; ++e) { float v = gl[tid][e]; if (v > mx) { mx = v; bi = e; } }
        float den = 0.f;
#pragma unroll
        for (int e = 0; e < nE; ++e) { float g = expf(gl[tid][e] - mx); gl[tid][e] = g; den += g; }
        float inv = 1.f / den;
#pragma unroll
        for (int e = 0; e < nE; ++e) gl[tid][e] *= inv;
        idxo[tb + tid] = bi;
        gateval[tb + tid] = inv;             // gate of argmax = 1/den
        atomicAdd(&hist[bi], 1);
    }
    __syncthreads();
    if (tid < nE) {
        float s = 0.f;
        for (int t = 0; t < GT; ++t) s += gl[t][tid];
        atomicAdd(&me_g[tid], s);
        counts[blockIdx.x * nE + tid] = hist[tid];
    }
}

// ---------------- scan across blocks + aux loss ----------------
__global__ __launch_bounds__(1024) void k_scan(
    const int* __restrict__ counts, int* __restrict__ offsets,
    const float* __restrict__ me_g, float* __restrict__ loss_out)
{
    __shared__ int tot[nE];
    const int w = threadIdx.x >> 6;
    const int lane = threadIdx.x & 63;
    for (int e = w; e < nE; e += 16) {
        int v[4]; int s = 0;
#pragma unroll
        for (int i = 0; i < 4; ++i) { v[i] = counts[(lane * 4 + i) * nE + e]; s += v[i]; }
        int incl = s;
#pragma unroll
        for (int d = 1; d < 64; d <<= 1) {
            int o = __shfl_up(incl, d);
            if (lane >= d) incl += o;
        }
        int run = incl - s;
#pragma unroll
        for (int i = 0; i < 4; ++i) { offsets[(lane * 4 + i) * nE + e] = run; run += v[i]; }
        int total = __shfl(incl, 63);
        if (lane == 0) tot[e] = total;
    }
    __syncthreads();
    if (threadIdx.x < 64) {
        float val = (threadIdx.x < nE) ? me_g[threadIdx.x] * (float)tot[threadIdx.x] : 0.f;
#pragma unroll
        for (int d = 32; d >= 1; d >>= 1) val += __shfl_xor(val, d);
        if (threadIdx.x == 0)
            *loss_out = val * ((float)nE / ((float)nS * (float)nS));
    }
}

// ---------------- per-token slot assignment; zero dropped rows ----------------
__global__ __launch_bounds__(64) void k_assign(
    const int* __restrict__ idxi, const int* __restrict__ offsets,
    int* __restrict__ inv_slot, float* __restrict__ y)
{
    __shared__ int drop[64];
    __shared__ int ndrop;
    const int lane = threadIdx.x;
    const int t = blockIdx.x * 64 + lane;
    const int e = idxi[t];
    if (lane == 0) ndrop = 0;
    __syncthreads();
    int rank = 0;
#pragma unroll
    for (int ee = 0; ee < nE; ++ee) {
        unsigned long long m = __ballot(e == ee);
        if (e == ee) rank = __popcll(m & ((1ull << lane) - 1ull));
    }
    const int loc = offsets[blockIdx.x * nE + e] + rank;
    if (loc < nCAP) {
        inv_slot[e * nCAP + loc] = t;
    } else {
        int p = atomicAdd(&ndrop, 1);
        drop[p] = t;
    }
    __syncthreads();
    const int nd = ndrop;
    for (int i = 0; i < nd; ++i) {
        const int tt = drop[i];
        float4 z = {0.f, 0.f, 0.f, 0.f};
        for (int c = lane; c < nD / 4; c += 64)
            *(float4*)&y[(size_t)tt * nD + c * 4] = z;
    }
}

// ---------------- weight transpose + fp32->bf16 ----------------
__global__ __launch_bounds__(256) void k_transpose(
    const float* __restrict__ w1, const float* __restrict__ w2,
    unsigned short* __restrict__ w1t, unsigned short* __restrict__ w2t)
{
    __shared__ unsigned short tile[64][68];
    const float* src = blockIdx.z ? w2 : w1;
    unsigned short* dst = blockIdx.z ? w2t : w1t;
    const int e = blockIdx.y;
    const int a0 = (blockIdx.x >> 4) * 64;
    const int b0 = (blockIdx.x & 15) * 64;
    const int tid = threadIdx.x;
#pragma unroll
    for (int i = 0; i < 4; ++i) {
        int f = tid + i * 256;
        int r = f >> 4, c4 = f & 15;
        const float4 v = *(const float4*)&src[((size_t)e * 1024 + a0 + r) * 1024 + b0 + c4 * 4];
        tile[r][c4*4+0] = f2bf(v.x); tile[r][c4*4+1] = f2bf(v.y);
        tile[r][c4*4+2] = f2bf(v.z); tile[r][c4*4+3] = f2bf(v.w);
    }
    __syncthreads();
#pragma unroll
    for (int i = 0; i < 4; ++i) {
        int f = tid + i * 256;
        int r = f >> 4, c4 = f & 15;
        unsigned long long pk = (unsigned long long)tile[c4*4+0][r]
            | ((unsigned long long)tile[c4*4+1][r] << 16)
            | ((unsigned long long)tile[c4*4+2][r] << 32)
            | ((unsigned long long)tile[c4*4+3][r] << 48);
        *(unsigned long long*)&dst[((size_t)e * 1024 + b0 + r) * 1024 + a0 + c4 * 4] = pk;
    }
}

// ---------------- expert GEMMs (m97 structure, 128x128xBK64) ----------------
// MODE 0: h = relu(gather(x_bf16) @ w1t^T), bf16 out
// MODE 1: y[token] = (h @ w2t^T) * gate, fp32 scatter
template <int MODE>
__global__ __launch_bounds__(256) void k_gemm(
    const unsigned short* __restrict__ Abase,
    const unsigned short* __restrict__ Bt,
    const int* __restrict__ inv_slot,
    const float* __restrict__ gateval,
    unsigned short* __restrict__ hout,
    float* __restrict__ y)
{
    __shared__ __attribute__((aligned(16))) unsigned short As[128 * 64];
    __shared__ __attribute__((aligned(16))) unsigned short Bs[128 * 64];

    const int tid = threadIdx.x;
    const int lane = tid & 63, w = tid >> 6;
    const int n0 = blockIdx.x * 128, m0 = blockIdx.y * 128, e = blockIdx.z;

    const unsigned short* gA[4];
    const unsigned short* gB[4];
    const int j = lane & 7;
#pragma unroll
    for (int s = 0; s < 4; ++s) {
        const int cw = s * 4 + w;              // 0..15
        const int row = cw * 8 + (lane >> 3);  // 0..127
        if (MODE == 0) {
            int tok = inv_slot[e * nCAP + m0 + row];
            if (tok < 0) tok = 0;
            gA[s] = Abase + (size_t)tok * nD + j * 8;
        } else {
            gA[s] = Abase + ((size_t)e * nCAP + m0 + row) * nH + j * 8;
        }
        gB[s] = Bt + ((size_t)e * 1024 + n0 + row) * 1024 + j * 8;
    }

    f32x4 acc[4][4];
#pragma unroll
    for (int a = 0; a < 4; ++a)
#pragma unroll
        for (int b = 0; b < 4; ++b) acc[a][b] = (f32x4){0.f, 0.f, 0.f, 0.f};

    const int wm = w >> 1, wn = w & 1;
    const int abyte = (wm * 64 + (lane & 15)) * 128 + (lane >> 4) * 16;
    const int bbyte = (wn * 64 + (lane & 15)) * 128 + (lane >> 4) * 16;

    for (int k0 = 0; k0 < 1024 / 64; ++k0) {
#pragma unroll
        for (int s = 0; s < 4; ++s) {
            gload16(gA[s] + k0 * 64, (char*)As + (s * 4 + w) * 1024);
            gload16(gB[s] + k0 * 64, (char*)Bs + (s * 4 + w) * 1024);
        }
        __syncthreads();
#pragma unroll
        for (int kk = 0; kk < 2; ++kk) {
            bf16x8 a[4], b[4];
#pragma unroll
            for (int mi = 0; mi < 4; ++mi)
                a[mi] = *(const bf16x8*)((const char*)As + abyte + mi * 2048 + kk * 64);
#pragma unroll
            for (int ni = 0; ni < 4; ++ni)
                b[ni] = *(const bf16x8*)((const char*)Bs + bbyte + ni * 2048 + kk * 64);
#pragma unroll
            for (int mi = 0; mi < 4; ++mi)
#pragma unroll
                for (int ni = 0; ni < 4; ++ni)
                    acc[mi][ni] = __builtin_amdgcn_mfma_f32_16x16x32_bf16(
                        a[mi], b[ni], acc[mi][ni], 0, 0, 0);
        }
        __syncthreads();
    }

    const int col_l = lane & 15, rg = lane >> 4;
    if (MODE == 0) {
#pragma unroll
        for (int mi = 0; mi < 4; ++mi) {
#pragma unroll
            for (int ni = 0; ni < 4; ++ni) {
                const f32x4 v = acc[mi][ni];
                const int n = n0 + wn * 64 + ni * 16 + col_l;
#pragma unroll
                for (int r = 0; r < 4; ++r) {
                    const int m = m0 + wm * 64 + mi * 16 + rg * 4 + r;
                    const float f = v[r] > 0.f ? v[r] : 0.f;
                    hout[((size_t)e * nCAP + m) * nH + n] = f2bf(f);
                }
            }
        }
    } else {
#pragma unroll
        for (int mi = 0; mi < 4; ++mi) {
            int tok[4]; float gv[4];
#pragma unroll
            for (int r = 0; r < 4; ++r) {
                const int m = m0 + wm * 64 + mi * 16 + rg * 4 + r;
                tok[r] = inv_slot[e * nCAP + m];
                gv[r] = (tok[r] >= 0) ? gateval[tok[r]] : 0.f;
            }
#pragma unroll
            for (int ni = 0; ni < 4; ++ni) {
                const f32x4 v = acc[mi][ni];
                const int n = n0 + wn * 64 + ni * 16 + col_l;
#pragma unroll
                for (int r = 0; r < 4; ++r) {
                    if (tok[r] >= 0)
                        y[(size_t)tok[r] * nD + n] = v[r] * gv[r];
                }
            }
        }
    }
}

extern "C" void kernel_launch(void* const* d_in, const int* in_sizes, int n_in,
                              void* d_out, int out_size, void* d_ws, size_t ws_size,
                              hipStream_t stream) {
    const float* x  = (const float*)d_in[0];
    const float* wg = (const float*)d_in[1];
    const float* w1 = (const float*)d_in[2];
    const float* w2 = (const float*)d_in[3];
    float* y = (float*)d_out;
    float* loss = y + (size_t)nS * nD;

    char* ws = (char*)d_ws;
    unsigned short* w1t  = (unsigned short*)(ws);                       // 64MB
    unsigned short* w2t  = (unsigned short*)(ws + (64ull << 20));       // 64MB
    unsigned short* hbuf = (unsigned short*)(ws + (128ull << 20));      // 32MB
    unsigned short* xbf  = (unsigned short*)(ws + (160ull << 20));      // 32MB
    char* p = ws + (192ull << 20);
    int*   idxb    = (int*)p;   p += (size_t)nS * 4;
    float* gateval = (float*)p; p += (size_t)nS * 4;
    int*   counts  = (int*)p;   p += (size_t)GB * nE * 4;
    int*   offsets = (int*)p;   p += (size_t)GB * nE * 4;
    float* me_g    = (float*)p; p += 4096;
    int*   inv_slot= (int*)p;

    k_init<<<64, 256, 0, stream>>>(inv_slot, me_g);
    k_gate<<<GB, 128, 0, stream>>>(x, wg, xbf, idxb, gateval, counts, me_g);
    k_scan<<<1, 1024, 0, stream>>>(counts, offsets, me_g, loss);
    k_assign<<<GB, 64, 0, stream>>>(idxb, offsets, inv_slot, y);
    k_transpose<<<dim3(256, 32, 2), 256, 0, stream>>>(w1, w2, w1t, w2t);
    k_gemm<0><<<dim3(8, 4, 32), 256, 0, stream>>>(xbf, w1t, inv_slot, gateval, hbuf, y);
    k_gemm<1><<<dim3(8, 4, 32), 256, 0, stream>>>(hbuf, w2t, inv_slot, gateval, hbuf, y);
}